// Round 14
// baseline (999.352 us; speedup 1.0000x reference)
//
#include <hip/hip_runtime.h>
#include <hip/hip_fp16.h>

#define TPB 256
#define BSH 9          // 512 nodes per bucket
#define BUCK (1 << BSH)
#define NBMAX 1024
#define CAP 6144
#define EPB 2048       // edges per block in bcount/partA

using f16x8 = __attribute__((ext_vector_type(8))) _Float16;
using f32x4 = __attribute__((ext_vector_type(4))) float;

// ---------------- half helpers ----------------

union H8 { uint4 u; __half2 h[4]; f16x8 f; };
union H4 { uint2 u; __half2 h[2]; };

__device__ inline void h8_to_f(const H8 v, float4& a, float4& b) {
    float2 f0 = __half22float2(v.h[0]);
    float2 f1 = __half22float2(v.h[1]);
    float2 f2 = __half22float2(v.h[2]);
    float2 f3 = __half22float2(v.h[3]);
    a = make_float4(f0.x, f0.y, f1.x, f1.y);
    b = make_float4(f2.x, f2.y, f3.x, f3.y);
}
__device__ inline H8 f_to_h8(float4 a, float4 b) {
    H8 r;
    r.h[0] = __floats2half2_rn(a.x, a.y);
    r.h[1] = __floats2half2_rn(a.z, a.w);
    r.h[2] = __floats2half2_rn(b.x, b.y);
    r.h[3] = __floats2half2_rn(b.z, b.w);
    return r;
}
__device__ inline float4 f4z() { return make_float4(0.f, 0.f, 0.f, 0.f); }
__device__ inline float4 f4axpy(float4 a, float s, float4 c) {
    return make_float4(fmaf(a.x, s, c.x), fmaf(a.y, s, c.y), fmaf(a.z, s, c.z), fmaf(a.w, s, c.w));
}
__device__ inline float4 f4relu_aff(float4 h, float4 sc, float4 sb) {
    return make_float4(fmaxf(fmaf(h.x, sc.x, sb.x), 0.f), fmaxf(fmaf(h.y, sc.y, sb.y), 0.f),
                       fmaxf(fmaf(h.z, sc.z, sb.z), 0.f), fmaxf(fmaf(h.w, sc.w, sb.w), 0.f));
}

// ---------------- CSR build, bucket-local ----------------

__global__ __launch_bounds__(256) void k_bcount(const int* __restrict__ dst, int E,
                                                int* __restrict__ bcount, int nb) {
    __shared__ int hist[NBMAX];
    for (int i = threadIdx.x; i < nb; i += 256) hist[i] = 0;
    __syncthreads();
    const int e0 = blockIdx.x * EPB;
#pragma unroll
    for (int k = 0; k < EPB / 256; ++k) {
        int e = e0 + k * 256 + threadIdx.x;
        if (e < E) atomicAdd(&hist[dst[e] >> BSH], 1);
    }
    __syncthreads();
    for (int i = threadIdx.x; i < nb; i += 256) {
        int h = hist[i];
        if (h) atomicAdd(&bcount[i], h);
    }
}

__global__ void k_bscan(const int* __restrict__ bcount, int* __restrict__ bbase,
                        int* __restrict__ bcur, int nb, int E, int* __restrict__ row_ptr,
                        int n) {
    if (threadIdx.x == 0 && blockIdx.x == 0) {
        int run = 0;
        for (int i = 0; i < nb; ++i) {
            bbase[i] = run;
            bcur[i] = run;
            run += bcount[i];
        }
        bbase[nb] = E;
        row_ptr[n] = E;
    }
}

__global__ __launch_bounds__(256) void k_partA(const int* __restrict__ src,
                                               const int* __restrict__ dst, int E,
                                               int* __restrict__ bcur, int* __restrict__ bin,
                                               int nb) {
    __shared__ int hist[NBMAX];
    __shared__ int base[NBMAX];
    for (int i = threadIdx.x; i < nb; i += 256) hist[i] = 0;
    __syncthreads();
    const int e0 = blockIdx.x * EPB;
#pragma unroll
    for (int k = 0; k < EPB / 256; ++k) {
        int e = e0 + k * 256 + threadIdx.x;
        if (e < E) atomicAdd(&hist[dst[e] >> BSH], 1);
    }
    __syncthreads();
    for (int i = threadIdx.x; i < nb; i += 256) {
        int h = hist[i];
        base[i] = h ? atomicAdd(&bcur[i], h) : 0;
        hist[i] = 0;
    }
    __syncthreads();
#pragma unroll
    for (int k = 0; k < EPB / 256; ++k) {
        int e = e0 + k * 256 + threadIdx.x;
        if (e < E) {
            int d = dst[e];
            int b = d >> BSH;
            int off = atomicAdd(&hist[b], 1);
            bin[base[b] + off] = ((d & (BUCK - 1)) << 19) | src[e];
        }
    }
}

__global__ __launch_bounds__(256) void k_csr_bucket(const int* __restrict__ bin,
                                                    const int* __restrict__ bbase,
                                                    int* __restrict__ row_ptr,
                                                    float* __restrict__ dis,
                                                    int* __restrict__ csr_src, int n) {
    __shared__ int ldeg[BUCK];
    __shared__ int lcur[BUCK];
    __shared__ int ts[256];
    __shared__ int stage[CAP];
    const int b = blockIdx.x;
    const int node0 = b << BSH;
    const int nodes = min(BUCK, n - node0);
    const int ebeg = bbase[b], eend = bbase[b + 1];
    const int cnt = eend - ebeg;

    for (int i = threadIdx.x; i < BUCK; i += 256) ldeg[i] = 0;
    __syncthreads();
    for (int e = ebeg + threadIdx.x; e < eend; e += 256)
        atomicAdd(&ldeg[bin[e] >> 19], 1);
    __syncthreads();

    const int b2 = threadIdx.x * 2;
    int v0 = ldeg[b2], v1 = ldeg[b2 + 1];
    ts[threadIdx.x] = v0 + v1;
    __syncthreads();
    for (int off = 1; off < 256; off <<= 1) {
        int t = (threadIdx.x >= off) ? ts[threadIdx.x - off] : 0;
        __syncthreads();
        ts[threadIdx.x] += t;
        __syncthreads();
    }
    int o0 = (threadIdx.x == 0) ? 0 : ts[threadIdx.x - 1];
    int o1 = o0 + v0;
    lcur[b2] = o0;
    lcur[b2 + 1] = o1;
    if (b2 < nodes) {
        row_ptr[node0 + b2] = ebeg + o0;
        dis[node0 + b2] = rsqrtf((float)(v0 + 1));
    }
    if (b2 + 1 < nodes) {
        row_ptr[node0 + b2 + 1] = ebeg + o1;
        dis[node0 + b2 + 1] = rsqrtf((float)(v1 + 1));
    }
    __syncthreads();

    for (int e = ebeg + threadIdx.x; e < eend; e += 256) {
        int p = bin[e];
        int pos = atomicAdd(&lcur[p >> 19], 1);
        int s = p & 0x7FFFF;
        if (pos < CAP) stage[pos] = s;
        else csr_src[ebeg + pos] = s;
    }
    __syncthreads();
    int m = cnt < CAP ? cnt : CAP;
    for (int i = threadIdx.x; i < m; i += 256) csr_src[ebeg + i] = stage[i];
}

// ---------------- VALU matmul (small layers): 4 nodes x 8 ch/thread, fused stats ----------

template <int FI, int FO, bool STATS, bool IN_F32>
__global__ __launch_bounds__(TPB) void k_mm_v(const void* __restrict__ tin,
                                              const float* __restrict__ W,
                                              __half* __restrict__ z,
                                              float* __restrict__ stats, int n) {
    constexpr int GROUPS = FO / 8;
    constexpr int NPB = (TPB / GROUPS) * 4;
    __shared__ float sW[FI * FO];
    __shared__ float sred[STATS ? TPB * 16 : 1];
    for (int i = threadIdx.x; i < FI * FO; i += TPB) sW[i] = W[i];
    __syncthreads();

    const int g = threadIdx.x % GROUPS;
    const int nl = threadIdx.x / GROUPS;
    const int nbase = blockIdx.x * NPB + nl * 4;

    float4 acc0[4], acc1[4];
#pragma unroll
    for (int j = 0; j < 4; ++j) { acc0[j] = f4z(); acc1[j] = f4z(); }

    for (int k = 0; k < FI; k += 4) {
        float4 wv0[4], wv1[4];
#pragma unroll
        for (int kk = 0; kk < 4; ++kk) {
            wv0[kk] = *(const float4*)&sW[(k + kk) * FO + g * 8];
            wv1[kk] = *(const float4*)&sW[(k + kk) * FO + g * 8 + 4];
        }
#pragma unroll
        for (int j = 0; j < 4; ++j) {
            int node = nbase + j;
            float rk[4] = {0.f, 0.f, 0.f, 0.f};
            if (node < n) {
                if (IN_F32) {
                    float4 rv = *(const float4*)((const float*)tin + (size_t)node * FI + k);
                    rk[0] = rv.x; rk[1] = rv.y; rk[2] = rv.z; rk[3] = rv.w;
                } else {
                    H4 hv;
                    hv.u = *(const uint2*)((const __half*)tin + (size_t)node * FI + k);
                    float2 f0 = __half22float2(hv.h[0]);
                    float2 f1 = __half22float2(hv.h[1]);
                    rk[0] = f0.x; rk[1] = f0.y; rk[2] = f1.x; rk[3] = f1.y;
                }
            }
#pragma unroll
            for (int kk = 0; kk < 4; ++kk) {
                acc0[j] = f4axpy(wv0[kk], rk[kk], acc0[j]);
                acc1[j] = f4axpy(wv1[kk], rk[kk], acc1[j]);
            }
        }
    }

#pragma unroll
    for (int j = 0; j < 4; ++j) {
        int node = nbase + j;
        if (node < n) {
            H8 o = f_to_h8(acc0[j], acc1[j]);
            *(uint4*)(z + (size_t)node * FO + g * 8) = o.u;
        }
    }

    if (STATS) {
        float4 s0 = f4z(), s1 = f4z(), q0 = f4z(), q1 = f4z();
#pragma unroll
        for (int j = 0; j < 4; ++j) {
            s0.x += acc0[j].x; s0.y += acc0[j].y; s0.z += acc0[j].z; s0.w += acc0[j].w;
            s1.x += acc1[j].x; s1.y += acc1[j].y; s1.z += acc1[j].z; s1.w += acc1[j].w;
            q0.x = fmaf(acc0[j].x, acc0[j].x, q0.x); q0.y = fmaf(acc0[j].y, acc0[j].y, q0.y);
            q0.z = fmaf(acc0[j].z, acc0[j].z, q0.z); q0.w = fmaf(acc0[j].w, acc0[j].w, q0.w);
            q1.x = fmaf(acc1[j].x, acc1[j].x, q1.x); q1.y = fmaf(acc1[j].y, acc1[j].y, q1.y);
            q1.z = fmaf(acc1[j].z, acc1[j].z, q1.z); q1.w = fmaf(acc1[j].w, acc1[j].w, q1.w);
        }
        float* slot = &sred[threadIdx.x * 16];
        *(float4*)(slot + 0) = s0;
        *(float4*)(slot + 4) = s1;
        *(float4*)(slot + 8) = q0;
        *(float4*)(slot + 12) = q1;
        __syncthreads();
        if (threadIdx.x < FO * 2) {
            int c = threadIdx.x % FO;
            int m = threadIdx.x / FO;
            int g2 = c / 8, ci = c % 8;
            float a = 0.f;
            for (int nl2 = 0; nl2 < TPB / GROUPS; ++nl2)
                a += sred[(nl2 * GROUPS + g2) * 16 + m * 8 + ci];
            atomicAdd(&stats[m * FO + c], a);
        }
    }
}

// ---------------- standalone MFMA matmul (FO=64): z = t @ W, fused stats ----------------

template <int FI>
__global__ __launch_bounds__(256) void k_mm_mfma(const __half* __restrict__ tin,
                                                 const float* __restrict__ W,
                                                 __half* __restrict__ z,
                                                 float* __restrict__ stats, int n) {
    constexpr int KC = FI / 32;
    constexpr int RSW = FI + 8;
    __shared__ _Float16 wt[64 * RSW];
    __shared__ float sstat[2][4][64];
    for (int i = threadIdx.x; i < FI * 64; i += 256) {
        int k = i >> 6, nn = i & 63;
        wt[nn * RSW + k] = (_Float16)W[i];
    }
    __syncthreads();

    const int lane = threadIdx.x & 63;
    const int wv = threadIdx.x >> 6;
    const int quad = lane >> 4;
    const int mcol = lane & 15;
    const int rowbase = blockIdx.x * 256 + wv * 64;

    f16x8 b[4][KC];
#pragma unroll
    for (int t = 0; t < 4; ++t)
#pragma unroll
        for (int c = 0; c < KC; ++c)
            b[t][c] = *(const f16x8*)&wt[(t * 16 + mcol) * RSW + c * 32 + quad * 8];

    float s[4] = {0.f, 0.f, 0.f, 0.f}, q[4] = {0.f, 0.f, 0.f, 0.f};

#pragma unroll
    for (int rt = 0; rt < 4; ++rt) {
        const int row0 = rowbase + rt * 16;
        const int arow = row0 + mcol;
        f16x8 a[KC];
#pragma unroll
        for (int c = 0; c < KC; ++c) {
            if (arow < n)
                a[c] = *(const f16x8*)((const _Float16*)tin + (size_t)arow * FI + c * 32 +
                                       quad * 8);
            else
                a[c] = f16x8{0, 0, 0, 0, 0, 0, 0, 0};
        }
        f32x4 acc[4];
#pragma unroll
        for (int t = 0; t < 4; ++t) acc[t] = f32x4{0.f, 0.f, 0.f, 0.f};
#pragma unroll
        for (int t = 0; t < 4; ++t)
#pragma unroll
            for (int c = 0; c < KC; ++c)
                acc[t] = __builtin_amdgcn_mfma_f32_16x16x32_f16(a[c], b[t][c], acc[t], 0, 0, 0);

#pragma unroll
        for (int t = 0; t < 4; ++t)
#pragma unroll
            for (int r = 0; r < 4; ++r) {
                int row = row0 + quad * 4 + r;
                if (row < n) z[(size_t)row * 64 + t * 16 + mcol] = __float2half(acc[t][r]);
            }
#pragma unroll
        for (int t = 0; t < 4; ++t) {
            s[t] += acc[t][0] + acc[t][1] + acc[t][2] + acc[t][3];
            q[t] += acc[t][0] * acc[t][0] + acc[t][1] * acc[t][1] + acc[t][2] * acc[t][2] +
                    acc[t][3] * acc[t][3];
        }
    }

#pragma unroll
    for (int off = 16; off < 64; off <<= 1) {
#pragma unroll
        for (int t = 0; t < 4; ++t) {
            s[t] += __shfl_xor(s[t], off, 64);
            q[t] += __shfl_xor(q[t], off, 64);
        }
    }
    if (lane < 16) {
#pragma unroll
        for (int t = 0; t < 4; ++t) {
            sstat[0][wv][t * 16 + lane] = s[t];
            sstat[1][wv][t * 16 + lane] = q[t];
        }
    }
    __syncthreads();
    if (threadIdx.x < 128) {
        int c = threadIdx.x & 63, m = threadIdx.x >> 6;
        float a4 = sstat[m][0][c] + sstat[m][1][c] + sstat[m][2][c] + sstat[m][3][c];
        atomicAdd(&stats[m * 64 + c], a4);
    }
}

// ---------------- fused gather(BN+ReLU) + MFMA matmul, block-staged LDS tile (FI=32) ------

template <int FI, int ROWS>
__global__ __launch_bounds__(256) void k_gmm(const int* __restrict__ row_ptr,
                                             const int* __restrict__ csr_src,
                                             const float* __restrict__ dis,
                                             const __half* __restrict__ zin,
                                             const float* __restrict__ W,
                                             const float* __restrict__ stats_in,
                                             const float* __restrict__ gg,
                                             const float* __restrict__ be, float inv_n,
                                             __half* __restrict__ zout,
                                             float* __restrict__ stats_out, int n) {
    constexpr int RSW = FI + 8;
    constexpr int RST = FI + 8;
    constexpr int PARTS = FI / 16;
    constexpr int KC = FI / 32;
    constexpr int RT = ROWS / 64;
    constexpr int NTASK = ROWS * PARTS / 256;
    __shared__ _Float16 wt[64 * RSW];
    __shared__ _Float16 ttile[ROWS * RST];
    __shared__ float saff[2 * FI];
    __shared__ float sstat[2][4][64];

    for (int i = threadIdx.x; i < FI * 64; i += 256) {
        int k = i >> 6, nn = i & 63;
        wt[nn * RSW + k] = (_Float16)W[i];
    }
    if (threadIdx.x < FI) {
        int c = threadIdx.x;
        float mu = stats_in[c] * inv_n;
        float var = stats_in[FI + c] * inv_n - mu * mu;
        float s = gg[c] * rsqrtf(var + 1e-5f);
        saff[c] = s;
        saff[FI + c] = fmaf(-mu, s, be[c]);
    }
    __syncthreads();

    const int nbase = blockIdx.x * ROWS;

    // ---- gather phase ----
#pragma unroll
    for (int it = 0; it < NTASK; ++it) {
        int tt = it * 256 + threadIdx.x;
        int nl = tt / PARTS;
        int part = tt % PARTS;
        int node = nbase + nl;
        int cbase = part * 16;
        float4 sc[4], sb[4];
#pragma unroll
        for (int v = 0; v < 4; ++v) {
            sc[v] = *(const float4*)&saff[cbase + v * 4];
            sb[v] = *(const float4*)&saff[FI + cbase + v * 4];
        }
        float4 acc[4] = {f4z(), f4z(), f4z(), f4z()};
        if (node < n) {
            float dn = dis[node];
            float w0 = dn * dn;
            {
                const uint4* zp = (const uint4*)(zin + (size_t)node * FI + cbase);
#pragma unroll
                for (int l = 0; l < 2; ++l) {
                    H8 hv; hv.u = zp[l];
                    float4 a, b;
                    h8_to_f(hv, a, b);
                    a = f4relu_aff(a, sc[2 * l], sb[2 * l]);
                    b = f4relu_aff(b, sc[2 * l + 1], sb[2 * l + 1]);
                    acc[2 * l] = f4axpy(a, w0, acc[2 * l]);
                    acc[2 * l + 1] = f4axpy(b, w0, acc[2 * l + 1]);
                }
            }
            int beg = row_ptr[node], end = row_ptr[node + 1];
            int j = beg;
            for (; j + 1 < end; j += 2) {
                int s0 = csr_src[j], s1 = csr_src[j + 1];
                float wA = dn * dis[s0];
                float wB = dn * dis[s1];
                const uint4* pA = (const uint4*)(zin + (size_t)s0 * FI + cbase);
                const uint4* pB = (const uint4*)(zin + (size_t)s1 * FI + cbase);
                uint4 rA0 = pA[0], rA1 = pA[1], rB0 = pB[0], rB1 = pB[1];
                H8 hv; float4 a, b;
                hv.u = rA0; h8_to_f(hv, a, b);
                a = f4relu_aff(a, sc[0], sb[0]); b = f4relu_aff(b, sc[1], sb[1]);
                acc[0] = f4axpy(a, wA, acc[0]); acc[1] = f4axpy(b, wA, acc[1]);
                hv.u = rA1; h8_to_f(hv, a, b);
                a = f4relu_aff(a, sc[2], sb[2]); b = f4relu_aff(b, sc[3], sb[3]);
                acc[2] = f4axpy(a, wA, acc[2]); acc[3] = f4axpy(b, wA, acc[3]);
                hv.u = rB0; h8_to_f(hv, a, b);
                a = f4relu_aff(a, sc[0], sb[0]); b = f4relu_aff(b, sc[1], sb[1]);
                acc[0] = f4axpy(a, wB, acc[0]); acc[1] = f4axpy(b, wB, acc[1]);
                hv.u = rB1; h8_to_f(hv, a, b);
                a = f4relu_aff(a, sc[2], sb[2]); b = f4relu_aff(b, sc[3], sb[3]);
                acc[2] = f4axpy(a, wB, acc[2]); acc[3] = f4axpy(b, wB, acc[3]);
            }
            if (j < end) {
                int s0 = csr_src[j];
                float wA = dn * dis[s0];
                const uint4* pA = (const uint4*)(zin + (size_t)s0 * FI + cbase);
#pragma unroll
                for (int l = 0; l < 2; ++l) {
                    H8 hv; hv.u = pA[l];
                    float4 a, b;
                    h8_to_f(hv, a, b);
                    a = f4relu_aff(a, sc[2 * l], sb[2 * l]);
                    b = f4relu_aff(b, sc[2 * l + 1], sb[2 * l + 1]);
                    acc[2 * l] = f4axpy(a, wA, acc[2 * l]);
                    acc[2 * l + 1] = f4axpy(b, wA, acc[2 * l + 1]);
                }
            }
        }
        _Float16* tp = &ttile[nl * RST + cbase];
        *(uint4*)(tp) = f_to_h8(acc[0], acc[1]).u;
        *(uint4*)(tp + 8) = f_to_h8(acc[2], acc[3]).u;
    }
    __syncthreads();

    // ---- MFMA phase ----
    const int lane = threadIdx.x & 63;
    const int wv = threadIdx.x >> 6;
    const int quad = lane >> 4;
    const int mcol = lane & 15;

    f16x8 bf[4][KC];
#pragma unroll
    for (int t = 0; t < 4; ++t)
#pragma unroll
        for (int c = 0; c < KC; ++c)
            bf[t][c] = *(const f16x8*)&wt[(t * 16 + mcol) * RSW + c * 32 + quad * 8];

    float s[4] = {0.f, 0.f, 0.f, 0.f}, q[4] = {0.f, 0.f, 0.f, 0.f};

#pragma unroll
    for (int rt = 0; rt < RT; ++rt) {
        const int lrow0 = wv * RT * 16 + rt * 16;
        f16x8 a[KC];
#pragma unroll
        for (int c = 0; c < KC; ++c)
            a[c] = *(const f16x8*)&ttile[(lrow0 + mcol) * RST + c * 32 + quad * 8];
        f32x4 acc[4];
#pragma unroll
        for (int t = 0; t < 4; ++t) acc[t] = f32x4{0.f, 0.f, 0.f, 0.f};
#pragma unroll
        for (int t = 0; t < 4; ++t)
#pragma unroll
            for (int c = 0; c < KC; ++c)
                acc[t] = __builtin_amdgcn_mfma_f32_16x16x32_f16(a[c], bf[t][c], acc[t], 0, 0, 0);

#pragma unroll
        for (int t = 0; t < 4; ++t)
#pragma unroll
            for (int r = 0; r < 4; ++r) {
                int row = nbase + lrow0 + quad * 4 + r;
                if (row < n) zout[(size_t)row * 64 + t * 16 + mcol] = __float2half(acc[t][r]);
            }
#pragma unroll
        for (int t = 0; t < 4; ++t) {
            s[t] += acc[t][0] + acc[t][1] + acc[t][2] + acc[t][3];
            q[t] += acc[t][0] * acc[t][0] + acc[t][1] * acc[t][1] + acc[t][2] * acc[t][2] +
                    acc[t][3] * acc[t][3];
        }
    }

#pragma unroll
    for (int off = 16; off < 64; off <<= 1) {
#pragma unroll
        for (int t = 0; t < 4; ++t) {
            s[t] += __shfl_xor(s[t], off, 64);
            q[t] += __shfl_xor(q[t], off, 64);
        }
    }
    if (lane < 16) {
#pragma unroll
        for (int t = 0; t < 4; ++t) {
            sstat[0][wv][t * 16 + lane] = s[t];
            sstat[1][wv][t * 16 + lane] = q[t];
        }
    }
    __syncthreads();
    if (threadIdx.x < 128) {
        int c = threadIdx.x & 63, m = threadIdx.x >> 6;
        float a4 = sstat[m][0][c] + sstat[m][1][c] + sstat[m][2][c] + sstat[m][3][c];
        atomicAdd(&stats_out[m * 64 + c], a4);
    }
}

// ---------------- CSR gather standalone, GW=min(F,16), unroll x4, optional stats ----

template <int F, bool AFFINE, bool STATS>
__global__ __launch_bounds__(TPB) void k_gather(const int* __restrict__ row_ptr,
                                                const int* __restrict__ csr_src,
                                                const float* __restrict__ dis,
                                                const __half* __restrict__ z,
                                                __half* __restrict__ t,
                                                const float* __restrict__ stats_in,
                                                const float* __restrict__ gg,
                                                const float* __restrict__ be, float inv_n,
                                                float* __restrict__ stats_out, int n) {
    constexpr int GW = (F < 16) ? F : 16;
    constexpr int PARTS = F / GW;
    constexpr int NV = GW / 4;
    constexpr int NL = GW / 8;
    __shared__ float sred[STATS ? TPB * 16 : 1];
    int tid = blockIdx.x * blockDim.x + threadIdx.x;
    int node = tid / PARTS;
    int part = tid % PARTS;
    bool active = node < n;
    if (!STATS && !active) return;
    const int cbase = part * GW;

    float4 sc[NV], sb[NV];
    if (AFFINE) {
#pragma unroll
        for (int v = 0; v < NV; ++v) {
            float scv[4], sbv[4];
#pragma unroll
            for (int u = 0; u < 4; ++u) {
                int c = cbase + v * 4 + u;
                float mu = stats_in[c] * inv_n;
                float var = stats_in[F + c] * inv_n - mu * mu;
                float s = gg[c] * rsqrtf(var + 1e-5f);
                scv[u] = s;
                sbv[u] = fmaf(-mu, s, be[c]);
            }
            sc[v] = make_float4(scv[0], scv[1], scv[2], scv[3]);
            sb[v] = make_float4(sbv[0], sbv[1], sbv[2], sbv[3]);
        }
    }

    float4 acc[NV];
#pragma unroll
    for (int v = 0; v < NV; ++v) acc[v] = f4z();

    if (active) {
        float dn = dis[node];
        float w0 = dn * dn;
        {
            const uint4* zp = (const uint4*)(z + (size_t)node * F + cbase);
#pragma unroll
            for (int l = 0; l < NL; ++l) {
                H8 hv; hv.u = zp[l];
                float4 a, b;
                h8_to_f(hv, a, b);
                if (AFFINE) { a = f4relu_aff(a, sc[2 * l], sb[2 * l]); b = f4relu_aff(b, sc[2 * l + 1], sb[2 * l + 1]); }
                acc[2 * l] = f4axpy(a, w0, acc[2 * l]);
                acc[2 * l + 1] = f4axpy(b, w0, acc[2 * l + 1]);
            }
        }
        int beg = row_ptr[node], end = row_ptr[node + 1];
        int j = beg;
        for (; j + 3 < end; j += 4) {
            int s0 = csr_src[j], s1 = csr_src[j + 1], s2 = csr_src[j + 2], s3 = csr_src[j + 3];
            float wA = dn * dis[s0];
            float wB = dn * dis[s1];
            float wC = dn * dis[s2];
            float wD = dn * dis[s3];
            const uint4* pA = (const uint4*)(z + (size_t)s0 * F + cbase);
            const uint4* pB = (const uint4*)(z + (size_t)s1 * F + cbase);
            const uint4* pC = (const uint4*)(z + (size_t)s2 * F + cbase);
            const uint4* pD = (const uint4*)(z + (size_t)s3 * F + cbase);
            uint4 rA[NL], rB[NL], rC[NL], rD[NL];
#pragma unroll
            for (int l = 0; l < NL; ++l) { rA[l] = pA[l]; rB[l] = pB[l]; rC[l] = pC[l]; rD[l] = pD[l]; }
#pragma unroll
            for (int l = 0; l < NL; ++l) {
                H8 hv; float4 a, b;
                hv.u = rA[l]; h8_to_f(hv, a, b);
                if (AFFINE) { a = f4relu_aff(a, sc[2 * l], sb[2 * l]); b = f4relu_aff(b, sc[2 * l + 1], sb[2 * l + 1]); }
                acc[2 * l] = f4axpy(a, wA, acc[2 * l]); acc[2 * l + 1] = f4axpy(b, wA, acc[2 * l + 1]);
                hv.u = rB[l]; h8_to_f(hv, a, b);
                if (AFFINE) { a = f4relu_aff(a, sc[2 * l], sb[2 * l]); b = f4relu_aff(b, sc[2 * l + 1], sb[2 * l + 1]); }
                acc[2 * l] = f4axpy(a, wB, acc[2 * l]); acc[2 * l + 1] = f4axpy(b, wB, acc[2 * l + 1]);
                hv.u = rC[l]; h8_to_f(hv, a, b);
                if (AFFINE) { a = f4relu_aff(a, sc[2 * l], sb[2 * l]); b = f4relu_aff(b, sc[2 * l + 1], sb[2 * l + 1]); }
                acc[2 * l] = f4axpy(a, wC, acc[2 * l]); acc[2 * l + 1] = f4axpy(b, wC, acc[2 * l + 1]);
                hv.u = rD[l]; h8_to_f(hv, a, b);
                if (AFFINE) { a = f4relu_aff(a, sc[2 * l], sb[2 * l]); b = f4relu_aff(b, sc[2 * l + 1], sb[2 * l + 1]); }
                acc[2 * l] = f4axpy(a, wD, acc[2 * l]); acc[2 * l + 1] = f4axpy(b, wD, acc[2 * l + 1]);
            }
        }
        for (; j < end; ++j) {
            int s0 = csr_src[j];
            float wA = dn * dis[s0];
            const uint4* pA = (const uint4*)(z + (size_t)s0 * F + cbase);
#pragma unroll
            for (int l = 0; l < NL; ++l) {
                H8 hv; hv.u = pA[l];
                float4 a, b;
                h8_to_f(hv, a, b);
                if (AFFINE) { a = f4relu_aff(a, sc[2 * l], sb[2 * l]); b = f4relu_aff(b, sc[2 * l + 1], sb[2 * l + 1]); }
                acc[2 * l] = f4axpy(a, wA, acc[2 * l]);
                acc[2 * l + 1] = f4axpy(b, wA, acc[2 * l + 1]);
            }
        }
        uint4* tp = (uint4*)(t + (size_t)node * F + cbase);
#pragma unroll
        for (int l = 0; l < NL; ++l) tp[l] = f_to_h8(acc[2 * l], acc[2 * l + 1]).u;
    }

    if (STATS) {  // only instantiated with F==8 (PARTS==1, NV==2)
        float* slot = &sred[threadIdx.x * 16];
        *(float4*)(slot + 0) = acc[0];
        *(float4*)(slot + 4) = acc[1];
        float4 q0 = make_float4(acc[0].x * acc[0].x, acc[0].y * acc[0].y, acc[0].z * acc[0].z,
                                acc[0].w * acc[0].w);
        float4 q1 = make_float4(acc[1].x * acc[1].x, acc[1].y * acc[1].y, acc[1].z * acc[1].z,
                                acc[1].w * acc[1].w);
        *(float4*)(slot + 8) = q0;
        *(float4*)(slot + 12) = q1;
        __syncthreads();
        if (threadIdx.x < 16) {
            int c = threadIdx.x % 8;
            int m = threadIdx.x / 8;
            float a = 0.f;
            for (int t2 = 0; t2 < TPB; ++t2) a += sred[t2 * 16 + m * 8 + c];
            atomicAdd(&stats_out[m * 8 + c], a);
        }
    }
}

// ---------------- segment multi-aggregation (applies final BN affine, no relu) ----------------

__device__ inline int bsearch_seg(const int* __restrict__ bidx, int n, int s) {
    int lo = 0, hi = n;
    while (lo < hi) {
        int mid = (lo + hi) >> 1;
        if (bidx[mid] < s) lo = mid + 1; else hi = mid;
    }
    return lo;
}

__global__ __launch_bounds__(TPB) void k_seg_reduce(const __half* __restrict__ z,
                                                    const int* __restrict__ bidx, int n,
                                                    float* __restrict__ aggin,
                                                    const float* __restrict__ stats,
                                                    const float* __restrict__ gg,
                                                    const float* __restrict__ be, float inv_n) {
    __shared__ int sbounds[2];
    int s = blockIdx.x;
    if (threadIdx.x < 2) sbounds[threadIdx.x] = bsearch_seg(bidx, n, s + threadIdx.x);
    __syncthreads();
    int start = sbounds[0], end = sbounds[1];
    int c = threadIdx.x & 63;
    float mu = stats[c] * inv_n;
    float var = stats[64 + c] * inv_n - mu * mu;
    float scv = gg[c] * rsqrtf(var + 1e-5f);
    float sbv = fmaf(-mu, scv, be[c]);
    int r0 = start + (threadIdx.x >> 6);
    float sm = 0.f, sm2 = 0.f, mn = INFINITY, mx = -INFINITY;
    for (int r = r0; r < end; r += 4) {
        float v = fmaf(__half2float(z[(size_t)r * 64 + c]), scv, sbv);
        sm += v;
        sm2 = fmaf(v, v, sm2);
        mn = fminf(mn, v);
        mx = fmaxf(mx, v);
    }
    __shared__ float s_sm[TPB], s_sm2[TPB], s_mn[TPB], s_mx[TPB];
    s_sm[threadIdx.x] = sm;
    s_sm2[threadIdx.x] = sm2;
    s_mn[threadIdx.x] = mn;
    s_mx[threadIdx.x] = mx;
    __syncthreads();
    if (threadIdx.x < 64) {
        for (int t = threadIdx.x + 64; t < TPB; t += 64) {
            sm += s_sm[t];
            sm2 += s_sm2[t];
            mn = fminf(mn, s_mn[t]);
            mx = fmaxf(mx, s_mx[t]);
        }
        int count = end - start;
        float cnt = (float)(count > 0 ? count : 1);
        float mean = sm / cnt;
        float var2 = sm2 / cnt - mean * mean;
        if (var2 < 0.f) var2 = 0.f;
        float sd = sqrtf(var2 + 1e-5f);
        if (count <= 0) { mn = 0.f; mx = 0.f; }
        aggin[s * 256 + c] = mean;
        aggin[s * 256 + 64 + c] = mn;
        aggin[s * 256 + 128 + c] = mx;
        aggin[s * 256 + 192 + c] = sd;
    }
}

__global__ __launch_bounds__(64) void k_proj(const float* __restrict__ aggin,
                                             const float* __restrict__ Wp,
                                             const float* __restrict__ bp,
                                             float* __restrict__ proj) {
    __shared__ float sA[256];
    int s = blockIdx.x;
    int j = threadIdx.x;
    for (int k = j; k < 256; k += 64) sA[k] = aggin[s * 256 + k];
    __syncthreads();
    float acc = bp[j];
#pragma unroll 8
    for (int k = 0; k < 256; ++k) acc = fmaf(sA[k], Wp[k * 64 + j], acc);
    proj[s * 64 + j] = acc;
}

__global__ void k_pack(const float* __restrict__ proj, const int* __restrict__ num_sp,
                       float* __restrict__ out, int B, int S) {
    int idx = blockIdx.x * blockDim.x + threadIdx.x;
    int total = B * 64 * 196;
    if (idx >= total) return;
    int ii = idx % 14;
    int jj = (idx / 14) % 14;
    int c = (idx / 196) % 64;
    int b = idx / (196 * 64);
    int p = ii * 14 + jj;
    int off = 0;
    for (int k = 0; k < b; ++k) off += num_sp[k];
    float v = 0.f;
    if (p < num_sp[b]) {
        int s = off + p;
        if (s > S - 1) s = S - 1;
        v = proj[s * 64 + c];
    }
    out[idx] = v;
}

// ---------------- launch ----------------

extern "C" void kernel_launch(void* const* d_in, const int* in_sizes, int n_in,
                              void* d_out, int out_size, void* d_ws, size_t ws_size,
                              hipStream_t stream) {
    const float* x = (const float*)d_in[0];
    const int* ei = (const int*)d_in[1];
    const int* bidx = (const int*)d_in[2];
    const int* num_sp = (const int*)d_in[3];
    const float* Wl[5], * Gl[5], * BEl[5];
    for (int i = 0; i < 5; ++i) {
        Wl[i] = (const float*)d_in[4 + 4 * i];
        // bias skipped: per-channel constant cancels in training-mode BN
        Gl[i] = (const float*)d_in[6 + 4 * i];
        BEl[i] = (const float*)d_in[7 + 4 * i];
    }
    const float* Wp = (const float*)d_in[24];
    const float* bp = (const float*)d_in[25];

    const int n = in_sizes[0] / 24;
    const int E = in_sizes[1] / 2;
    const int B = in_sizes[3];
    const int S = 1200;
    const int* src = ei;
    const int* dst = ei + E;
    const float inv_n = 1.0f / (float)n;
    const int nb = (n + BUCK - 1) >> BSH;

    char* w = (char*)d_ws;
    __half* bufZ = (__half*)w;  w += (size_t)n * 64 * 2;
    __half* bufT = (__half*)w;  w += (size_t)n * 64 * 2;
    float* dis = (float*)w;     w += (size_t)n * 4;
    int* row_ptr = (int*)w;     w += (size_t)(n + 64) * 4;
    int* csr_src = (int*)w;     w += (size_t)E * 4;
    int* bin = (int*)w;         w += (size_t)E * 4;
    int* bcount = (int*)w;      w += (size_t)(nb + 64) * 4;
    int* bbase = (int*)w;       w += (size_t)(nb + 64) * 4;
    int* bcur = (int*)w;        w += (size_t)(nb + 64) * 4;
    float* stats_all = (float*)w; w += 5 * 128 * 4;
    float* aggin = (float*)w;   w += (size_t)S * 256 * 4;
    float* proj = (float*)w;    w += (size_t)S * 64 * 4;
    float* st0 = stats_all;
    float* st1 = stats_all + 128;
    float* st2 = stats_all + 256;
    float* st3 = stats_all + 384;
    float* st4 = stats_all + 512;

    // ---- CSR build (bucket-local) ----
    hipMemsetAsync(bcount, 0, (size_t)nb * 4, stream);
    hipMemsetAsync(stats_all, 0, 5 * 128 * 4, stream);
    k_bcount<<<(E + EPB - 1) / EPB, 256, 0, stream>>>(dst, E, bcount, nb);
    k_bscan<<<1, 64, 0, stream>>>(bcount, bbase, bcur, nb, E, row_ptr, n);
    k_partA<<<(E + EPB - 1) / EPB, 256, 0, stream>>>(src, dst, E, bcur, bin, nb);
    k_csr_bucket<<<nb, 256, 0, stream>>>(bin, bbase, row_ptr, dis, csr_src, n);

    // ---- Layer 1: m = x@W1 ; z1 = Agg(m) with fused stats ----
    k_mm_v<24, 8, false, true><<<(n + 1023) / 1024, TPB, 0, stream>>>(x, Wl[0], bufT, nullptr, n);
    k_gather<8, false, true><<<(n + TPB - 1) / TPB, TPB, 0, stream>>>(
        row_ptr, csr_src, dis, bufT, bufZ, nullptr, nullptr, nullptr, inv_n, st0, n);

    // ---- Layers 2-3: t = Agg(relu(bn(z))) ; z = t@W (stats fused) ----
    k_gather<8, true, false><<<(n + TPB - 1) / TPB, TPB, 0, stream>>>(
        row_ptr, csr_src, dis, bufZ, bufT, st0, Gl[0], BEl[0], inv_n, nullptr, n);
    k_mm_v<8, 16, true, false><<<(n + 511) / 512, TPB, 0, stream>>>(bufT, Wl[1], bufZ, st1, n);

    k_gather<16, true, false><<<(n + TPB - 1) / TPB, TPB, 0, stream>>>(
        row_ptr, csr_src, dis, bufZ, bufT, st1, Gl[1], BEl[1], inv_n, nullptr, n);
    k_mm_v<16, 32, true, false><<<(n + 255) / 256, TPB, 0, stream>>>(bufT, Wl[2], bufZ, st2, n);

    // ---- Layer 4: fused gather+MFMA, ROWS=128 (NTASK=1, smaller LDS, 2x grid) ----
    k_gmm<32, 128><<<(n + 127) / 128, 256, 0, stream>>>(
        row_ptr, csr_src, dis, bufZ, Wl[3], st2, Gl[2], BEl[2], inv_n, bufT, st3, n);

    // ---- Layer 5: unfused (standalone gather keeps occupancy/MLP) ----
    k_gather<64, true, false><<<(4 * n + TPB - 1) / TPB, TPB, 0, stream>>>(
        row_ptr, csr_src, dis, bufT, bufZ, st3, Gl[3], BEl[3], inv_n, nullptr, n);
    k_mm_mfma<64><<<(n + 255) / 256, 256, 0, stream>>>(bufZ, Wl[4], bufT, st4, n);

    // ---- tail ----
    k_seg_reduce<<<S, TPB, 0, stream>>>(bufT, bidx, n, aggin, st4, Gl[4], BEl[4], inv_n);
    k_proj<<<S, 64, 0, stream>>>(aggin, Wp, bp, proj);
    int total_out = B * 64 * 196;
    k_pack<<<(total_out + TPB - 1) / TPB, TPB, 0, stream>>>(proj, num_sp, (float*)d_out, B, S);
}

// Round 15
// 879.008 us; speedup vs baseline: 1.1369x; 1.1369x over previous
//
#include <hip/hip_runtime.h>
#include <hip/hip_fp16.h>

#define TPB 256
#define BSH 9          // 512 nodes per bucket
#define BUCK (1 << BSH)
#define NBMAX 1024
#define CAP 6144
#define BCAP 8192      // per-bucket bin window capacity (mean ~4092, +64 sigma)
#define EPB 8192       // edges per block in partA

using f16x8 = __attribute__((ext_vector_type(8))) _Float16;
using f32x4 = __attribute__((ext_vector_type(4))) float;

// ---------------- half helpers ----------------

union H8 { uint4 u; __half2 h[4]; f16x8 f; };
union H4 { uint2 u; __half2 h[2]; };

__device__ inline void h8_to_f(const H8 v, float4& a, float4& b) {
    float2 f0 = __half22float2(v.h[0]);
    float2 f1 = __half22float2(v.h[1]);
    float2 f2 = __half22float2(v.h[2]);
    float2 f3 = __half22float2(v.h[3]);
    a = make_float4(f0.x, f0.y, f1.x, f1.y);
    b = make_float4(f2.x, f2.y, f3.x, f3.y);
}
__device__ inline H8 f_to_h8(float4 a, float4 b) {
    H8 r;
    r.h[0] = __floats2half2_rn(a.x, a.y);
    r.h[1] = __floats2half2_rn(a.z, a.w);
    r.h[2] = __floats2half2_rn(b.x, b.y);
    r.h[3] = __floats2half2_rn(b.z, b.w);
    return r;
}
__device__ inline float4 f4z() { return make_float4(0.f, 0.f, 0.f, 0.f); }
__device__ inline float4 f4axpy(float4 a, float s, float4 c) {
    return make_float4(fmaf(a.x, s, c.x), fmaf(a.y, s, c.y), fmaf(a.z, s, c.z), fmaf(a.w, s, c.w));
}
__device__ inline float4 f4relu_aff(float4 h, float4 sc, float4 sb) {
    return make_float4(fmaxf(fmaf(h.x, sc.x, sb.x), 0.f), fmaxf(fmaf(h.y, sc.y, sb.y), 0.f),
                       fmaxf(fmaf(h.z, sc.z, sb.z), 0.f), fmaxf(fmaf(h.w, sc.w, sb.w), 0.f));
}

// ---------------- CSR build, bucket-local, single-pass binning ----------------

// partA: bin packed (dstLocal<<19 | src) into fixed-capacity per-bucket windows.
// bcur (zero-seeded) doubles as the per-bucket count afterwards.
__global__ __launch_bounds__(256) void k_partA(const int* __restrict__ src,
                                               const int* __restrict__ dst, int E,
                                               int* __restrict__ bcur, int* __restrict__ bin,
                                               int nb) {
    __shared__ int hist[NBMAX];
    __shared__ int base[NBMAX];
    for (int i = threadIdx.x; i < nb; i += 256) hist[i] = 0;
    __syncthreads();
    const int e0 = blockIdx.x * EPB;
#pragma unroll
    for (int k = 0; k < EPB / 256; ++k) {
        int e = e0 + k * 256 + threadIdx.x;
        if (e < E) atomicAdd(&hist[dst[e] >> BSH], 1);
    }
    __syncthreads();
    for (int i = threadIdx.x; i < nb; i += 256) {
        int h = hist[i];
        base[i] = h ? atomicAdd(&bcur[i], h) : 0;
        hist[i] = 0;
    }
    __syncthreads();
#pragma unroll
    for (int k = 0; k < EPB / 256; ++k) {
        int e = e0 + k * 256 + threadIdx.x;
        if (e < E) {
            int d = dst[e];
            int b = d >> BSH;
            int off = atomicAdd(&hist[b], 1);
            int pos = base[b] + off;
            if (pos < BCAP) bin[(size_t)b * BCAP + pos] = ((d & (BUCK - 1)) << 19) | src[e];
        }
    }
}

// prefix bucket counts -> bbase (dense CSR offsets)
__global__ void k_bscan(const int* __restrict__ bcnt, int* __restrict__ bbase, int nb, int E,
                        int* __restrict__ row_ptr, int n) {
    if (threadIdx.x == 0 && blockIdx.x == 0) {
        int run = 0;
        for (int i = 0; i < nb; ++i) {
            bbase[i] = run;
            run += bcnt[i];
        }
        bbase[nb] = run;
        row_ptr[n] = run;
    }
}

__global__ __launch_bounds__(256) void k_csr_bucket(const int* __restrict__ bin,
                                                    const int* __restrict__ bbase,
                                                    int* __restrict__ row_ptr,
                                                    float* __restrict__ dis,
                                                    int* __restrict__ csr_src, int n) {
    __shared__ int ldeg[BUCK];
    __shared__ int lcur[BUCK];
    __shared__ int ts[256];
    __shared__ int stage[CAP];
    const int b = blockIdx.x;
    const int node0 = b << BSH;
    const int nodes = min(BUCK, n - node0);
    const int ebeg = bbase[b], eend = bbase[b + 1];
    const int cnt = eend - ebeg;
    const int* wbin = bin + (size_t)b * BCAP;

    for (int i = threadIdx.x; i < BUCK; i += 256) ldeg[i] = 0;
    __syncthreads();
    for (int e = threadIdx.x; e < cnt; e += 256)
        atomicAdd(&ldeg[wbin[e] >> 19], 1);
    __syncthreads();

    const int b2 = threadIdx.x * 2;
    int v0 = ldeg[b2], v1 = ldeg[b2 + 1];
    ts[threadIdx.x] = v0 + v1;
    __syncthreads();
    for (int off = 1; off < 256; off <<= 1) {
        int t = (threadIdx.x >= off) ? ts[threadIdx.x - off] : 0;
        __syncthreads();
        ts[threadIdx.x] += t;
        __syncthreads();
    }
    int o0 = (threadIdx.x == 0) ? 0 : ts[threadIdx.x - 1];
    int o1 = o0 + v0;
    lcur[b2] = o0;
    lcur[b2 + 1] = o1;
    if (b2 < nodes) {
        row_ptr[node0 + b2] = ebeg + o0;
        dis[node0 + b2] = rsqrtf((float)(v0 + 1));
    }
    if (b2 + 1 < nodes) {
        row_ptr[node0 + b2 + 1] = ebeg + o1;
        dis[node0 + b2 + 1] = rsqrtf((float)(v1 + 1));
    }
    __syncthreads();

    for (int e = threadIdx.x; e < cnt; e += 256) {
        int p = wbin[e];
        int pos = atomicAdd(&lcur[p >> 19], 1);
        int s = p & 0x7FFFF;
        if (pos < CAP) stage[pos] = s;
        else csr_src[ebeg + pos] = s;
    }
    __syncthreads();
    int m = cnt < CAP ? cnt : CAP;
    for (int i = threadIdx.x; i < m; i += 256) csr_src[ebeg + i] = stage[i];
}

// ---------------- VALU matmul (small layers): 4 nodes x 8 ch/thread, fused stats ----------

template <int FI, int FO, bool STATS, bool IN_F32>
__global__ __launch_bounds__(TPB) void k_mm_v(const void* __restrict__ tin,
                                              const float* __restrict__ W,
                                              __half* __restrict__ z,
                                              float* __restrict__ stats, int n) {
    constexpr int GROUPS = FO / 8;
    constexpr int NPB = (TPB / GROUPS) * 4;
    __shared__ float sW[FI * FO];
    __shared__ float sred[STATS ? TPB * 16 : 1];
    for (int i = threadIdx.x; i < FI * FO; i += TPB) sW[i] = W[i];
    __syncthreads();

    const int g = threadIdx.x % GROUPS;
    const int nl = threadIdx.x / GROUPS;
    const int nbase = blockIdx.x * NPB + nl * 4;

    float4 acc0[4], acc1[4];
#pragma unroll
    for (int j = 0; j < 4; ++j) { acc0[j] = f4z(); acc1[j] = f4z(); }

    for (int k = 0; k < FI; k += 4) {
        float4 wv0[4], wv1[4];
#pragma unroll
        for (int kk = 0; kk < 4; ++kk) {
            wv0[kk] = *(const float4*)&sW[(k + kk) * FO + g * 8];
            wv1[kk] = *(const float4*)&sW[(k + kk) * FO + g * 8 + 4];
        }
#pragma unroll
        for (int j = 0; j < 4; ++j) {
            int node = nbase + j;
            float rk[4] = {0.f, 0.f, 0.f, 0.f};
            if (node < n) {
                if (IN_F32) {
                    float4 rv = *(const float4*)((const float*)tin + (size_t)node * FI + k);
                    rk[0] = rv.x; rk[1] = rv.y; rk[2] = rv.z; rk[3] = rv.w;
                } else {
                    H4 hv;
                    hv.u = *(const uint2*)((const __half*)tin + (size_t)node * FI + k);
                    float2 f0 = __half22float2(hv.h[0]);
                    float2 f1 = __half22float2(hv.h[1]);
                    rk[0] = f0.x; rk[1] = f0.y; rk[2] = f1.x; rk[3] = f1.y;
                }
            }
#pragma unroll
            for (int kk = 0; kk < 4; ++kk) {
                acc0[j] = f4axpy(wv0[kk], rk[kk], acc0[j]);
                acc1[j] = f4axpy(wv1[kk], rk[kk], acc1[j]);
            }
        }
    }

#pragma unroll
    for (int j = 0; j < 4; ++j) {
        int node = nbase + j;
        if (node < n) {
            H8 o = f_to_h8(acc0[j], acc1[j]);
            *(uint4*)(z + (size_t)node * FO + g * 8) = o.u;
        }
    }

    if (STATS) {
        float4 s0 = f4z(), s1 = f4z(), q0 = f4z(), q1 = f4z();
#pragma unroll
        for (int j = 0; j < 4; ++j) {
            s0.x += acc0[j].x; s0.y += acc0[j].y; s0.z += acc0[j].z; s0.w += acc0[j].w;
            s1.x += acc1[j].x; s1.y += acc1[j].y; s1.z += acc1[j].z; s1.w += acc1[j].w;
            q0.x = fmaf(acc0[j].x, acc0[j].x, q0.x); q0.y = fmaf(acc0[j].y, acc0[j].y, q0.y);
            q0.z = fmaf(acc0[j].z, acc0[j].z, q0.z); q0.w = fmaf(acc0[j].w, acc0[j].w, q0.w);
            q1.x = fmaf(acc1[j].x, acc1[j].x, q1.x); q1.y = fmaf(acc1[j].y, acc1[j].y, q1.y);
            q1.z = fmaf(acc1[j].z, acc1[j].z, q1.z); q1.w = fmaf(acc1[j].w, acc1[j].w, q1.w);
        }
        float* slot = &sred[threadIdx.x * 16];
        *(float4*)(slot + 0) = s0;
        *(float4*)(slot + 4) = s1;
        *(float4*)(slot + 8) = q0;
        *(float4*)(slot + 12) = q1;
        __syncthreads();
        if (threadIdx.x < FO * 2) {
            int c = threadIdx.x % FO;
            int m = threadIdx.x / FO;
            int g2 = c / 8, ci = c % 8;
            float a = 0.f;
            for (int nl2 = 0; nl2 < TPB / GROUPS; ++nl2)
                a += sred[(nl2 * GROUPS + g2) * 16 + m * 8 + ci];
            atomicAdd(&stats[m * FO + c], a);
        }
    }
}

// ---------------- standalone MFMA matmul (FO=64): z = t @ W, fused stats ----------------

template <int FI>
__global__ __launch_bounds__(256) void k_mm_mfma(const __half* __restrict__ tin,
                                                 const float* __restrict__ W,
                                                 __half* __restrict__ z,
                                                 float* __restrict__ stats, int n) {
    constexpr int KC = FI / 32;
    constexpr int RSW = FI + 8;
    __shared__ _Float16 wt[64 * RSW];
    __shared__ float sstat[2][4][64];
    for (int i = threadIdx.x; i < FI * 64; i += 256) {
        int k = i >> 6, nn = i & 63;
        wt[nn * RSW + k] = (_Float16)W[i];
    }
    __syncthreads();

    const int lane = threadIdx.x & 63;
    const int wv = threadIdx.x >> 6;
    const int quad = lane >> 4;
    const int mcol = lane & 15;
    const int rowbase = blockIdx.x * 256 + wv * 64;

    f16x8 b[4][KC];
#pragma unroll
    for (int t = 0; t < 4; ++t)
#pragma unroll
        for (int c = 0; c < KC; ++c)
            b[t][c] = *(const f16x8*)&wt[(t * 16 + mcol) * RSW + c * 32 + quad * 8];

    float s[4] = {0.f, 0.f, 0.f, 0.f}, q[4] = {0.f, 0.f, 0.f, 0.f};

#pragma unroll
    for (int rt = 0; rt < 4; ++rt) {
        const int row0 = rowbase + rt * 16;
        const int arow = row0 + mcol;
        f16x8 a[KC];
#pragma unroll
        for (int c = 0; c < KC; ++c) {
            if (arow < n)
                a[c] = *(const f16x8*)((const _Float16*)tin + (size_t)arow * FI + c * 32 +
                                       quad * 8);
            else
                a[c] = f16x8{0, 0, 0, 0, 0, 0, 0, 0};
        }
        f32x4 acc[4];
#pragma unroll
        for (int t = 0; t < 4; ++t) acc[t] = f32x4{0.f, 0.f, 0.f, 0.f};
#pragma unroll
        for (int t = 0; t < 4; ++t)
#pragma unroll
            for (int c = 0; c < KC; ++c)
                acc[t] = __builtin_amdgcn_mfma_f32_16x16x32_f16(a[c], b[t][c], acc[t], 0, 0, 0);

#pragma unroll
        for (int t = 0; t < 4; ++t)
#pragma unroll
            for (int r = 0; r < 4; ++r) {
                int row = row0 + quad * 4 + r;
                if (row < n) z[(size_t)row * 64 + t * 16 + mcol] = __float2half(acc[t][r]);
            }
#pragma unroll
        for (int t = 0; t < 4; ++t) {
            s[t] += acc[t][0] + acc[t][1] + acc[t][2] + acc[t][3];
            q[t] += acc[t][0] * acc[t][0] + acc[t][1] * acc[t][1] + acc[t][2] * acc[t][2] +
                    acc[t][3] * acc[t][3];
        }
    }

#pragma unroll
    for (int off = 16; off < 64; off <<= 1) {
#pragma unroll
        for (int t = 0; t < 4; ++t) {
            s[t] += __shfl_xor(s[t], off, 64);
            q[t] += __shfl_xor(q[t], off, 64);
        }
    }
    if (lane < 16) {
#pragma unroll
        for (int t = 0; t < 4; ++t) {
            sstat[0][wv][t * 16 + lane] = s[t];
            sstat[1][wv][t * 16 + lane] = q[t];
        }
    }
    __syncthreads();
    if (threadIdx.x < 128) {
        int c = threadIdx.x & 63, m = threadIdx.x >> 6;
        float a4 = sstat[m][0][c] + sstat[m][1][c] + sstat[m][2][c] + sstat[m][3][c];
        atomicAdd(&stats[m * 64 + c], a4);
    }
}

// ---------------- fused gather(BN+ReLU) + MFMA matmul, block-staged LDS tile (FI=32) ------

template <int FI, int ROWS>
__global__ __launch_bounds__(256) void k_gmm(const int* __restrict__ row_ptr,
                                             const int* __restrict__ csr_src,
                                             const float* __restrict__ dis,
                                             const __half* __restrict__ zin,
                                             const float* __restrict__ W,
                                             const float* __restrict__ stats_in,
                                             const float* __restrict__ gg,
                                             const float* __restrict__ be, float inv_n,
                                             __half* __restrict__ zout,
                                             float* __restrict__ stats_out, int n) {
    constexpr int RSW = FI + 8;
    constexpr int RST = FI + 8;
    constexpr int PARTS = FI / 16;
    constexpr int KC = FI / 32;
    constexpr int RT = ROWS / 64;
    constexpr int NTASK = ROWS * PARTS / 256;
    __shared__ _Float16 wt[64 * RSW];
    __shared__ _Float16 ttile[ROWS * RST];
    __shared__ float saff[2 * FI];
    __shared__ float sstat[2][4][64];

    for (int i = threadIdx.x; i < FI * 64; i += 256) {
        int k = i >> 6, nn = i & 63;
        wt[nn * RSW + k] = (_Float16)W[i];
    }
    if (threadIdx.x < FI) {
        int c = threadIdx.x;
        float mu = stats_in[c] * inv_n;
        float var = stats_in[FI + c] * inv_n - mu * mu;
        float s = gg[c] * rsqrtf(var + 1e-5f);
        saff[c] = s;
        saff[FI + c] = fmaf(-mu, s, be[c]);
    }
    __syncthreads();

    const int nbase = blockIdx.x * ROWS;

    // ---- gather phase ----
#pragma unroll
    for (int it = 0; it < NTASK; ++it) {
        int tt = it * 256 + threadIdx.x;
        int nl = tt / PARTS;
        int part = tt % PARTS;
        int node = nbase + nl;
        int cbase = part * 16;
        float4 sc[4], sb[4];
#pragma unroll
        for (int v = 0; v < 4; ++v) {
            sc[v] = *(const float4*)&saff[cbase + v * 4];
            sb[v] = *(const float4*)&saff[FI + cbase + v * 4];
        }
        float4 acc[4] = {f4z(), f4z(), f4z(), f4z()};
        if (node < n) {
            float dn = dis[node];
            float w0 = dn * dn;
            {
                const uint4* zp = (const uint4*)(zin + (size_t)node * FI + cbase);
#pragma unroll
                for (int l = 0; l < 2; ++l) {
                    H8 hv; hv.u = zp[l];
                    float4 a, b;
                    h8_to_f(hv, a, b);
                    a = f4relu_aff(a, sc[2 * l], sb[2 * l]);
                    b = f4relu_aff(b, sc[2 * l + 1], sb[2 * l + 1]);
                    acc[2 * l] = f4axpy(a, w0, acc[2 * l]);
                    acc[2 * l + 1] = f4axpy(b, w0, acc[2 * l + 1]);
                }
            }
            int beg = row_ptr[node], end = row_ptr[node + 1];
            int j = beg;
            for (; j + 1 < end; j += 2) {
                int s0 = csr_src[j], s1 = csr_src[j + 1];
                float wA = dn * dis[s0];
                float wB = dn * dis[s1];
                const uint4* pA = (const uint4*)(zin + (size_t)s0 * FI + cbase);
                const uint4* pB = (const uint4*)(zin + (size_t)s1 * FI + cbase);
                uint4 rA0 = pA[0], rA1 = pA[1], rB0 = pB[0], rB1 = pB[1];
                H8 hv; float4 a, b;
                hv.u = rA0; h8_to_f(hv, a, b);
                a = f4relu_aff(a, sc[0], sb[0]); b = f4relu_aff(b, sc[1], sb[1]);
                acc[0] = f4axpy(a, wA, acc[0]); acc[1] = f4axpy(b, wA, acc[1]);
                hv.u = rA1; h8_to_f(hv, a, b);
                a = f4relu_aff(a, sc[2], sb[2]); b = f4relu_aff(b, sc[3], sb[3]);
                acc[2] = f4axpy(a, wA, acc[2]); acc[3] = f4axpy(b, wA, acc[3]);
                hv.u = rB0; h8_to_f(hv, a, b);
                a = f4relu_aff(a, sc[0], sb[0]); b = f4relu_aff(b, sc[1], sb[1]);
                acc[0] = f4axpy(a, wB, acc[0]); acc[1] = f4axpy(b, wB, acc[1]);
                hv.u = rB1; h8_to_f(hv, a, b);
                a = f4relu_aff(a, sc[2], sb[2]); b = f4relu_aff(b, sc[3], sb[3]);
                acc[2] = f4axpy(a, wB, acc[2]); acc[3] = f4axpy(b, wB, acc[3]);
            }
            if (j < end) {
                int s0 = csr_src[j];
                float wA = dn * dis[s0];
                const uint4* pA = (const uint4*)(zin + (size_t)s0 * FI + cbase);
#pragma unroll
                for (int l = 0; l < 2; ++l) {
                    H8 hv; hv.u = pA[l];
                    float4 a, b;
                    h8_to_f(hv, a, b);
                    a = f4relu_aff(a, sc[2 * l], sb[2 * l]);
                    b = f4relu_aff(b, sc[2 * l + 1], sb[2 * l + 1]);
                    acc[2 * l] = f4axpy(a, wA, acc[2 * l]);
                    acc[2 * l + 1] = f4axpy(b, wA, acc[2 * l + 1]);
                }
            }
        }
        _Float16* tp = &ttile[nl * RST + cbase];
        *(uint4*)(tp) = f_to_h8(acc[0], acc[1]).u;
        *(uint4*)(tp + 8) = f_to_h8(acc[2], acc[3]).u;
    }
    __syncthreads();

    // ---- MFMA phase ----
    const int lane = threadIdx.x & 63;
    const int wv = threadIdx.x >> 6;
    const int quad = lane >> 4;
    const int mcol = lane & 15;

    f16x8 bf[4][KC];
#pragma unroll
    for (int t = 0; t < 4; ++t)
#pragma unroll
        for (int c = 0; c < KC; ++c)
            bf[t][c] = *(const f16x8*)&wt[(t * 16 + mcol) * RSW + c * 32 + quad * 8];

    float s[4] = {0.f, 0.f, 0.f, 0.f}, q[4] = {0.f, 0.f, 0.f, 0.f};

#pragma unroll
    for (int rt = 0; rt < RT; ++rt) {
        const int lrow0 = wv * RT * 16 + rt * 16;
        f16x8 a[KC];
#pragma unroll
        for (int c = 0; c < KC; ++c)
            a[c] = *(const f16x8*)&ttile[(lrow0 + mcol) * RST + c * 32 + quad * 8];
        f32x4 acc[4];
#pragma unroll
        for (int t = 0; t < 4; ++t) acc[t] = f32x4{0.f, 0.f, 0.f, 0.f};
#pragma unroll
        for (int t = 0; t < 4; ++t)
#pragma unroll
            for (int c = 0; c < KC; ++c)
                acc[t] = __builtin_amdgcn_mfma_f32_16x16x32_f16(a[c], bf[t][c], acc[t], 0, 0, 0);

#pragma unroll
        for (int t = 0; t < 4; ++t)
#pragma unroll
            for (int r = 0; r < 4; ++r) {
                int row = nbase + lrow0 + quad * 4 + r;
                if (row < n) zout[(size_t)row * 64 + t * 16 + mcol] = __float2half(acc[t][r]);
            }
#pragma unroll
        for (int t = 0; t < 4; ++t) {
            s[t] += acc[t][0] + acc[t][1] + acc[t][2] + acc[t][3];
            q[t] += acc[t][0] * acc[t][0] + acc[t][1] * acc[t][1] + acc[t][2] * acc[t][2] +
                    acc[t][3] * acc[t][3];
        }
    }

#pragma unroll
    for (int off = 16; off < 64; off <<= 1) {
#pragma unroll
        for (int t = 0; t < 4; ++t) {
            s[t] += __shfl_xor(s[t], off, 64);
            q[t] += __shfl_xor(q[t], off, 64);
        }
    }
    if (lane < 16) {
#pragma unroll
        for (int t = 0; t < 4; ++t) {
            sstat[0][wv][t * 16 + lane] = s[t];
            sstat[1][wv][t * 16 + lane] = q[t];
        }
    }
    __syncthreads();
    if (threadIdx.x < 128) {
        int c = threadIdx.x & 63, m = threadIdx.x >> 6;
        float a4 = sstat[m][0][c] + sstat[m][1][c] + sstat[m][2][c] + sstat[m][3][c];
        atomicAdd(&stats_out[m * 64 + c], a4);
    }
}

// ---------------- CSR gather standalone, GW=min(F,16), unroll x4, optional stats ----

template <int F, bool AFFINE, bool STATS>
__global__ __launch_bounds__(TPB) void k_gather(const int* __restrict__ row_ptr,
                                                const int* __restrict__ csr_src,
                                                const float* __restrict__ dis,
                                                const __half* __restrict__ z,
                                                __half* __restrict__ t,
                                                const float* __restrict__ stats_in,
                                                const float* __restrict__ gg,
                                                const float* __restrict__ be, float inv_n,
                                                float* __restrict__ stats_out, int n) {
    constexpr int GW = (F < 16) ? F : 16;
    constexpr int PARTS = F / GW;
    constexpr int NV = GW / 4;
    constexpr int NL = GW / 8;
    __shared__ float sred[STATS ? TPB * 16 : 1];
    int tid = blockIdx.x * blockDim.x + threadIdx.x;
    int node = tid / PARTS;
    int part = tid % PARTS;
    bool active = node < n;
    if (!STATS && !active) return;
    const int cbase = part * GW;

    float4 sc[NV], sb[NV];
    if (AFFINE) {
#pragma unroll
        for (int v = 0; v < NV; ++v) {
            float scv[4], sbv[4];
#pragma unroll
            for (int u = 0; u < 4; ++u) {
                int c = cbase + v * 4 + u;
                float mu = stats_in[c] * inv_n;
                float var = stats_in[F + c] * inv_n - mu * mu;
                float s = gg[c] * rsqrtf(var + 1e-5f);
                scv[u] = s;
                sbv[u] = fmaf(-mu, s, be[c]);
            }
            sc[v] = make_float4(scv[0], scv[1], scv[2], scv[3]);
            sb[v] = make_float4(sbv[0], sbv[1], sbv[2], sbv[3]);
        }
    }

    float4 acc[NV];
#pragma unroll
    for (int v = 0; v < NV; ++v) acc[v] = f4z();

    if (active) {
        float dn = dis[node];
        float w0 = dn * dn;
        {
            const uint4* zp = (const uint4*)(z + (size_t)node * F + cbase);
#pragma unroll
            for (int l = 0; l < NL; ++l) {
                H8 hv; hv.u = zp[l];
                float4 a, b;
                h8_to_f(hv, a, b);
                if (AFFINE) { a = f4relu_aff(a, sc[2 * l], sb[2 * l]); b = f4relu_aff(b, sc[2 * l + 1], sb[2 * l + 1]); }
                acc[2 * l] = f4axpy(a, w0, acc[2 * l]);
                acc[2 * l + 1] = f4axpy(b, w0, acc[2 * l + 1]);
            }
        }
        int beg = row_ptr[node], end = row_ptr[node + 1];
        int j = beg;
        for (; j + 3 < end; j += 4) {
            int s0 = csr_src[j], s1 = csr_src[j + 1], s2 = csr_src[j + 2], s3 = csr_src[j + 3];
            float wA = dn * dis[s0];
            float wB = dn * dis[s1];
            float wC = dn * dis[s2];
            float wD = dn * dis[s3];
            const uint4* pA = (const uint4*)(z + (size_t)s0 * F + cbase);
            const uint4* pB = (const uint4*)(z + (size_t)s1 * F + cbase);
            const uint4* pC = (const uint4*)(z + (size_t)s2 * F + cbase);
            const uint4* pD = (const uint4*)(z + (size_t)s3 * F + cbase);
            uint4 rA[NL], rB[NL], rC[NL], rD[NL];
#pragma unroll
            for (int l = 0; l < NL; ++l) { rA[l] = pA[l]; rB[l] = pB[l]; rC[l] = pC[l]; rD[l] = pD[l]; }
#pragma unroll
            for (int l = 0; l < NL; ++l) {
                H8 hv; float4 a, b;
                hv.u = rA[l]; h8_to_f(hv, a, b);
                if (AFFINE) { a = f4relu_aff(a, sc[2 * l], sb[2 * l]); b = f4relu_aff(b, sc[2 * l + 1], sb[2 * l + 1]); }
                acc[2 * l] = f4axpy(a, wA, acc[2 * l]); acc[2 * l + 1] = f4axpy(b, wA, acc[2 * l + 1]);
                hv.u = rB[l]; h8_to_f(hv, a, b);
                if (AFFINE) { a = f4relu_aff(a, sc[2 * l], sb[2 * l]); b = f4relu_aff(b, sc[2 * l + 1], sb[2 * l + 1]); }
                acc[2 * l] = f4axpy(a, wB, acc[2 * l]); acc[2 * l + 1] = f4axpy(b, wB, acc[2 * l + 1]);
                hv.u = rC[l]; h8_to_f(hv, a, b);
                if (AFFINE) { a = f4relu_aff(a, sc[2 * l], sb[2 * l]); b = f4relu_aff(b, sc[2 * l + 1], sb[2 * l + 1]); }
                acc[2 * l] = f4axpy(a, wC, acc[2 * l]); acc[2 * l + 1] = f4axpy(b, wC, acc[2 * l + 1]);
                hv.u = rD[l]; h8_to_f(hv, a, b);
                if (AFFINE) { a = f4relu_aff(a, sc[2 * l], sb[2 * l]); b = f4relu_aff(b, sc[2 * l + 1], sb[2 * l + 1]); }
                acc[2 * l] = f4axpy(a, wD, acc[2 * l]); acc[2 * l + 1] = f4axpy(b, wD, acc[2 * l + 1]);
            }
        }
        for (; j < end; ++j) {
            int s0 = csr_src[j];
            float wA = dn * dis[s0];
            const uint4* pA = (const uint4*)(z + (size_t)s0 * F + cbase);
#pragma unroll
            for (int l = 0; l < NL; ++l) {
                H8 hv; hv.u = pA[l];
                float4 a, b;
                h8_to_f(hv, a, b);
                if (AFFINE) { a = f4relu_aff(a, sc[2 * l], sb[2 * l]); b = f4relu_aff(b, sc[2 * l + 1], sb[2 * l + 1]); }
                acc[2 * l] = f4axpy(a, wA, acc[2 * l]);
                acc[2 * l + 1] = f4axpy(b, wA, acc[2 * l + 1]);
            }
        }
        uint4* tp = (uint4*)(t + (size_t)node * F + cbase);
#pragma unroll
        for (int l = 0; l < NL; ++l) tp[l] = f_to_h8(acc[2 * l], acc[2 * l + 1]).u;
    }

    if (STATS) {  // only instantiated with F==8 (PARTS==1, NV==2)
        float* slot = &sred[threadIdx.x * 16];
        *(float4*)(slot + 0) = acc[0];
        *(float4*)(slot + 4) = acc[1];
        float4 q0 = make_float4(acc[0].x * acc[0].x, acc[0].y * acc[0].y, acc[0].z * acc[0].z,
                                acc[0].w * acc[0].w);
        float4 q1 = make_float4(acc[1].x * acc[1].x, acc[1].y * acc[1].y, acc[1].z * acc[1].z,
                                acc[1].w * acc[1].w);
        *(float4*)(slot + 8) = q0;
        *(float4*)(slot + 12) = q1;
        __syncthreads();
        if (threadIdx.x < 16) {
            int c = threadIdx.x % 8;
            int m = threadIdx.x / 8;
            float a = 0.f;
            for (int t2 = 0; t2 < TPB; ++t2) a += sred[t2 * 16 + m * 8 + c];
            atomicAdd(&stats_out[m * 8 + c], a);
        }
    }
}

// ---------------- segment multi-aggregation (applies final BN affine, no relu) ----------------

__device__ inline int bsearch_seg(const int* __restrict__ bidx, int n, int s) {
    int lo = 0, hi = n;
    while (lo < hi) {
        int mid = (lo + hi) >> 1;
        if (bidx[mid] < s) lo = mid + 1; else hi = mid;
    }
    return lo;
}

__global__ __launch_bounds__(TPB) void k_seg_reduce(const __half* __restrict__ z,
                                                    const int* __restrict__ bidx, int n,
                                                    float* __restrict__ aggin,
                                                    const float* __restrict__ stats,
                                                    const float* __restrict__ gg,
                                                    const float* __restrict__ be, float inv_n) {
    __shared__ int sbounds[2];
    int s = blockIdx.x;
    if (threadIdx.x < 2) sbounds[threadIdx.x] = bsearch_seg(bidx, n, s + threadIdx.x);
    __syncthreads();
    int start = sbounds[0], end = sbounds[1];
    int c = threadIdx.x & 63;
    float mu = stats[c] * inv_n;
    float var = stats[64 + c] * inv_n - mu * mu;
    float scv = gg[c] * rsqrtf(var + 1e-5f);
    float sbv = fmaf(-mu, scv, be[c]);
    int r0 = start + (threadIdx.x >> 6);
    float sm = 0.f, sm2 = 0.f, mn = INFINITY, mx = -INFINITY;
    for (int r = r0; r < end; r += 4) {
        float v = fmaf(__half2float(z[(size_t)r * 64 + c]), scv, sbv);
        sm += v;
        sm2 = fmaf(v, v, sm2);
        mn = fminf(mn, v);
        mx = fmaxf(mx, v);
    }
    __shared__ float s_sm[TPB], s_sm2[TPB], s_mn[TPB], s_mx[TPB];
    s_sm[threadIdx.x] = sm;
    s_sm2[threadIdx.x] = sm2;
    s_mn[threadIdx.x] = mn;
    s_mx[threadIdx.x] = mx;
    __syncthreads();
    if (threadIdx.x < 64) {
        for (int t = threadIdx.x + 64; t < TPB; t += 64) {
            sm += s_sm[t];
            sm2 += s_sm2[t];
            mn = fminf(mn, s_mn[t]);
            mx = fmaxf(mx, s_mx[t]);
        }
        int count = end - start;
        float cnt = (float)(count > 0 ? count : 1);
        float mean = sm / cnt;
        float var2 = sm2 / cnt - mean * mean;
        if (var2 < 0.f) var2 = 0.f;
        float sd = sqrtf(var2 + 1e-5f);
        if (count <= 0) { mn = 0.f; mx = 0.f; }
        aggin[s * 256 + c] = mean;
        aggin[s * 256 + 64 + c] = mn;
        aggin[s * 256 + 128 + c] = mx;
        aggin[s * 256 + 192 + c] = sd;
    }
}

__global__ __launch_bounds__(64) void k_proj(const float* __restrict__ aggin,
                                             const float* __restrict__ Wp,
                                             const float* __restrict__ bp,
                                             float* __restrict__ proj) {
    __shared__ float sA[256];
    int s = blockIdx.x;
    int j = threadIdx.x;
    for (int k = j; k < 256; k += 64) sA[k] = aggin[s * 256 + k];
    __syncthreads();
    float acc = bp[j];
#pragma unroll 8
    for (int k = 0; k < 256; ++k) acc = fmaf(sA[k], Wp[k * 64 + j], acc);
    proj[s * 64 + j] = acc;
}

__global__ void k_pack(const float* __restrict__ proj, const int* __restrict__ num_sp,
                       float* __restrict__ out, int B, int S) {
    int idx = blockIdx.x * blockDim.x + threadIdx.x;
    int total = B * 64 * 196;
    if (idx >= total) return;
    int ii = idx % 14;
    int jj = (idx / 14) % 14;
    int c = (idx / 196) % 64;
    int b = idx / (196 * 64);
    int p = ii * 14 + jj;
    int off = 0;
    for (int k = 0; k < b; ++k) off += num_sp[k];
    float v = 0.f;
    if (p < num_sp[b]) {
        int s = off + p;
        if (s > S - 1) s = S - 1;
        v = proj[s * 64 + c];
    }
    out[idx] = v;
}

// ---------------- launch ----------------

extern "C" void kernel_launch(void* const* d_in, const int* in_sizes, int n_in,
                              void* d_out, int out_size, void* d_ws, size_t ws_size,
                              hipStream_t stream) {
    const float* x = (const float*)d_in[0];
    const int* ei = (const int*)d_in[1];
    const int* bidx = (const int*)d_in[2];
    const int* num_sp = (const int*)d_in[3];
    const float* Wl[5], * Gl[5], * BEl[5];
    for (int i = 0; i < 5; ++i) {
        Wl[i] = (const float*)d_in[4 + 4 * i];
        // bias skipped: per-channel constant cancels in training-mode BN
        Gl[i] = (const float*)d_in[6 + 4 * i];
        BEl[i] = (const float*)d_in[7 + 4 * i];
    }
    const float* Wp = (const float*)d_in[24];
    const float* bp = (const float*)d_in[25];

    const int n = in_sizes[0] / 24;
    const int E = in_sizes[1] / 2;
    const int B = in_sizes[3];
    const int S = 1200;
    const int* src = ei;
    const int* dst = ei + E;
    const float inv_n = 1.0f / (float)n;
    const int nb = (n + BUCK - 1) >> BSH;

    char* w = (char*)d_ws;
    __half* bufZ = (__half*)w;  w += (size_t)n * 64 * 2;
    __half* bufT = (__half*)w;  w += (size_t)n * 64 * 2;
    float* dis = (float*)w;     w += (size_t)n * 4;
    int* row_ptr = (int*)w;     w += (size_t)(n + 64) * 4;
    int* csr_src = (int*)w;     w += (size_t)E * 4;
    int* bin = (int*)w;         w += (size_t)nb * BCAP * 4;
    int* bcur = (int*)w;        w += (size_t)(nb + 64) * 4;
    int* bbase = (int*)w;       w += (size_t)(nb + 64) * 4;
    float* stats_all = (float*)w; w += 5 * 128 * 4;
    float* aggin = (float*)w;   w += (size_t)S * 256 * 4;
    float* proj = (float*)w;    w += (size_t)S * 64 * 4;
    float* st0 = stats_all;
    float* st1 = stats_all + 128;
    float* st2 = stats_all + 256;
    float* st3 = stats_all + 384;
    float* st4 = stats_all + 512;

    // ---- CSR build (single-pass binning into fixed-capacity windows) ----
    hipMemsetAsync(bcur, 0, (size_t)nb * 4, stream);
    hipMemsetAsync(stats_all, 0, 5 * 128 * 4, stream);
    k_partA<<<(E + EPB - 1) / EPB, 256, 0, stream>>>(src, dst, E, bcur, bin, nb);
    k_bscan<<<1, 64, 0, stream>>>(bcur, bbase, nb, E, row_ptr, n);
    k_csr_bucket<<<nb, 256, 0, stream>>>(bin, bbase, row_ptr, dis, csr_src, n);

    // ---- Layer 1: m = x@W1 ; z1 = Agg(m) with fused stats ----
    k_mm_v<24, 8, false, true><<<(n + 1023) / 1024, TPB, 0, stream>>>(x, Wl[0], bufT, nullptr, n);
    k_gather<8, false, true><<<(n + TPB - 1) / TPB, TPB, 0, stream>>>(
        row_ptr, csr_src, dis, bufT, bufZ, nullptr, nullptr, nullptr, inv_n, st0, n);

    // ---- Layers 2-3: t = Agg(relu(bn(z))) ; z = t@W (stats fused) ----
    k_gather<8, true, false><<<(n + TPB - 1) / TPB, TPB, 0, stream>>>(
        row_ptr, csr_src, dis, bufZ, bufT, st0, Gl[0], BEl[0], inv_n, nullptr, n);
    k_mm_v<8, 16, true, false><<<(n + 511) / 512, TPB, 0, stream>>>(bufT, Wl[1], bufZ, st1, n);

    k_gather<16, true, false><<<(n + TPB - 1) / TPB, TPB, 0, stream>>>(
        row_ptr, csr_src, dis, bufZ, bufT, st1, Gl[1], BEl[1], inv_n, nullptr, n);
    k_mm_v<16, 32, true, false><<<(n + 255) / 256, TPB, 0, stream>>>(bufT, Wl[2], bufZ, st2, n);

    // ---- Layer 4: fused gather+MFMA, ROWS=256 (R13 winning config) ----
    k_gmm<32, 256><<<(n + 255) / 256, 256, 0, stream>>>(
        row_ptr, csr_src, dis, bufZ, Wl[3], st2, Gl[2], BEl[2], inv_n, bufT, st3, n);

    // ---- Layer 5: unfused (standalone gather keeps occupancy/MLP) ----
    k_gather<64, true, false><<<(4 * n + TPB - 1) / TPB, TPB, 0, stream>>>(
        row_ptr, csr_src, dis, bufT, bufZ, st3, Gl[3], BEl[3], inv_n, nullptr, n);
    k_mm_mfma<64><<<(n + 255) / 256, 256, 0, stream>>>(bufZ, Wl[4], bufT, st4, n);

    // ---- tail ----
    k_seg_reduce<<<S, TPB, 0, stream>>>(bufT, bidx, n, aggin, st4, Gl[4], BEl[4], inv_n);
    k_proj<<<S, 64, 0, stream>>>(aggin, Wp, bp, proj);
    int total_out = B * 64 * 196;
    k_pack<<<(total_out + TPB - 1) / TPB, TPB, 0, stream>>>(proj, num_sp, (float*)d_out, B, S);
}